// Round 2
// baseline (483.670 us; speedup 1.0000x reference)
//
#include <hip/hip_runtime.h>
#include <hip/hip_bf16.h>

// Problem: B=256, S=256, D=448, BS=32, NB=14. M = B*S = 65536.
// Folded formulation:
//   WA[t][j] = sum_l W_q[t][blk(j)*32+l] * SSM_A[blk(j)*32+l][j]   (block-diag fold)
//   a = x@WA, b = x@WB, c = x@WC ; s_g[n] = 0.1 * x @ rowblocksum(W_g)
//   lin = a+b+c ; quad = a*sA + b*sB + c*sC (per 32-block)
//   ssm = dw*LN(quad) + (1-dw)*LN(lin) + x ;  out = ssm @ W_o
//
// GEMM1: X(65536x448) @ Wcat(448x1386, padded N->1408) -> Z bf16
// GEMM2: ssm(65536x448) @ W_o(448x448, padded N->512) -> out f32

typedef unsigned short u16;
typedef unsigned int u32;
typedef __bf16 bf16x8 __attribute__((ext_vector_type(8)));
typedef float f32x4 __attribute__((ext_vector_type(4)));

#define D_DIM 448
#define M_DIM 65536
#define NCAT 1386
#define NCAT_PAD 1408
#define N2_PAD 512

__device__ __forceinline__ u16 f2bf(float f) {
    union { float f; u32 u; } v; v.f = f;
    u32 u = v.u;
    u32 r = (u + 0x7fffu + ((u >> 16) & 1u)) >> 16;
    return (u16)r;
}
__device__ __forceinline__ float bf2f(u16 h) {
    union { u32 u; float f; } v; v.u = ((u32)h) << 16;
    return v.f;
}

__device__ __forceinline__ void load_lds16(const void* g, void* l) {
    __builtin_amdgcn_global_load_lds(
        (const __attribute__((address_space(1))) void*)g,
        (__attribute__((address_space(3))) void*)l, 16, 0, 0);
}

// ---------------- prep: fold SSM block-diagonals into W, build WcatT (N-major) ----------------
// WcatT[j][t], j in [0,1408), t in [0,448). Row stride 448 (bf16).
__global__ __launch_bounds__(64) void prep_wcat(
    const float* __restrict__ Wq, const float* __restrict__ Wk, const float* __restrict__ Wv,
    const float* __restrict__ SA, const float* __restrict__ SB, const float* __restrict__ SC,
    u16* __restrict__ WcatT)
{
    const int j = blockIdx.x;
    const int lane = threadIdx.x;
    u16* dst = WcatT + (size_t)j * D_DIM;

    if (j >= NCAT) {            // pad rows -> zero
        for (int t = lane; t < D_DIM; t += 64) dst[t] = 0;
        return;
    }
    if (j < 3 * D_DIM) {        // folded block-diag columns
        const int g = j / D_DIM, jj = j % D_DIM, n = jj >> 5;
        const float* W = (g == 0) ? Wq : (g == 1) ? Wk : Wv;
        const float* Mm = (g == 0) ? SA : (g == 1) ? SB : SC;
        __shared__ float av[32];
        if (lane < 32) av[lane] = Mm[(size_t)(n * 32 + lane) * D_DIM + jj];
        __syncthreads();
        for (int t = lane; t < D_DIM; t += 64) {
            const float* wrow = W + (size_t)t * D_DIM + n * 32;
            float s = 0.f;
            #pragma unroll
            for (int l = 0; l < 32; ++l) s += wrow[l] * av[l];
            dst[t] = f2bf(s);
        }
    } else {                    // 0.1 * block row-sum columns (quad multipliers)
        const int js = j - 3 * D_DIM;
        const int g = js / 14, n = js % 14;
        const float* W = (g == 0) ? Wq : (g == 1) ? Wk : Wv;
        for (int t = lane; t < D_DIM; t += 64) {
            const float* wrow = W + (size_t)t * D_DIM + n * 32;
            float s = 0.f;
            #pragma unroll
            for (int l = 0; l < 32; ++l) s += wrow[l];
            dst[t] = f2bf(0.1f * s);
        }
    }
}

// WoT[o][d] = W_o[d][o], o in [0,512) padded, d in [0,448)
__global__ __launch_bounds__(256) void prep_wo(const float* __restrict__ Wo, u16* __restrict__ WoT) {
    const int idx = blockIdx.x * 256 + threadIdx.x;   // 512*448 total
    const int o = idx / D_DIM, d = idx % D_DIM;
    WoT[idx] = (o < D_DIM) ? f2bf(Wo[(size_t)d * D_DIM + o]) : (u16)0;
}

// x f32 -> bf16
__global__ __launch_bounds__(256) void cvt_x_kernel(const float* __restrict__ x, u16* __restrict__ xb) {
    const size_t i = ((size_t)blockIdx.x * 256 + threadIdx.x) * 4;
    float4 v = *reinterpret_cast<const float4*>(x + i);
    u16 o0 = f2bf(v.x), o1 = f2bf(v.y), o2 = f2bf(v.z), o3 = f2bf(v.w);
    u32 lo = (u32)o0 | ((u32)o1 << 16);
    u32 hi = (u32)o2 | ((u32)o3 << 16);
    u32* p = reinterpret_cast<u32*>(xb + i);
    p[0] = lo; p[1] = hi;
}

// ---------------- m97-style 128x128 bf16 GEMM, K=448, B given N-major (transposed) ----------------
template<bool BF16OUT>
__global__ __launch_bounds__(256) void gemm_bt(
    const u16* __restrict__ A,    // M x 448 bf16 row-major
    const u16* __restrict__ Bt,   // N x 448 bf16 row-major (i.e. B transposed)
    void* __restrict__ Cout,
    int ldc, int nreal)
{
    __shared__ u16 lA[128 * 32];
    __shared__ u16 lB[128 * 32];
    const int tid = threadIdx.x;
    const int wave = tid >> 6, lane = tid & 63;
    const int brow = blockIdx.y * 128;
    const int bcol = blockIdx.x * 128;
    const int wr = wave >> 1, wc = wave & 1;

    f32x4 acc[4][4];
    #pragma unroll
    for (int i = 0; i < 4; ++i)
        #pragma unroll
        for (int j = 0; j < 4; ++j) {
            f32x4 z = {0.f, 0.f, 0.f, 0.f};
            acc[i][j] = z;
        }

    const int lrow = lane & 15;
    const int kgrp = (lane >> 4) << 3;   // 0,8,16,24

    for (int kt = 0; kt < 14; ++kt) {
        const int k0 = kt * 32;
        // stage A and B tiles: each tile 128x32 bf16 = 512 x 16B chunks; 4 waves x 2 instr x 64 lanes
        #pragma unroll
        for (int i = 0; i < 2; ++i) {
            const int chunk = (wave * 2 + i) * 64 + lane;     // 0..511
            const int row = chunk >> 2, kk = (chunk & 3) << 3;
            load_lds16(A + (size_t)(brow + row) * D_DIM + k0 + kk,
                       lA + (size_t)(wave * 2 + i) * 64 * 8);
            load_lds16(Bt + (size_t)(bcol + row) * D_DIM + k0 + kk,
                       lB + (size_t)(wave * 2 + i) * 64 * 8);
        }
        __syncthreads();   // drains vmcnt before barrier (compiler-inserted)

        bf16x8 af[4];
        #pragma unroll
        for (int mi = 0; mi < 4; ++mi) {
            const int r = wr * 64 + mi * 16 + lrow;
            af[mi] = *reinterpret_cast<const bf16x8*>(&lA[r * 32 + kgrp]);
        }
        #pragma unroll
        for (int ni = 0; ni < 4; ++ni) {
            const int n = wc * 64 + ni * 16 + lrow;
            bf16x8 bfr = *reinterpret_cast<const bf16x8*>(&lB[n * 32 + kgrp]);
            #pragma unroll
            for (int mi = 0; mi < 4; ++mi)
                acc[mi][ni] = __builtin_amdgcn_mfma_f32_16x16x32_bf16(af[mi], bfr, acc[mi][ni], 0, 0, 0);
        }
        __syncthreads();
    }

    // epilogue: C/D layout col=lane&15, row=(lane>>4)*4+reg  [m89-verified]
    const int rbase = brow + wr * 64 + ((lane >> 4) << 2);
    const int cbase = bcol + wc * 64 + (lane & 15);
    #pragma unroll
    for (int mi = 0; mi < 4; ++mi) {
        #pragma unroll
        for (int ni = 0; ni < 4; ++ni) {
            const int col = cbase + ni * 16;
            #pragma unroll
            for (int r = 0; r < 4; ++r) {
                const int row = rbase + mi * 16 + r;
                const float v = acc[mi][ni][r];
                if (BF16OUT) {
                    ((u16*)Cout)[(size_t)row * ldc + col] = f2bf(v);
                } else {
                    if (col < nreal)
                        ((float*)Cout)[(size_t)row * nreal + col] = v;
                }
            }
        }
    }
}

// ---------------- row-wise epilogue: LN(lin), LN(quad), blend, residual -> ssm bf16 ----------------
__global__ __launch_bounds__(256) void ssm_epilogue(
    const u16* __restrict__ Z, const float* __restrict__ x,
    const float* __restrict__ gamma, const float* __restrict__ beta,
    const float* __restrict__ dynw, u16* __restrict__ ssm)
{
    const int row = blockIdx.x * 4 + (threadIdx.x >> 6);
    const int lane = threadIdx.x & 63;
    const u16* zr = Z + (size_t)row * NCAT_PAD;
    const float dwv = 1.0f / (1.0f + __expf(-dynw[0]));

    float lin[7], quad[7];
    float s0 = 0.f, s1 = 0.f, s2 = 0.f, s3 = 0.f;
    #pragma unroll
    for (int i = 0; i < 7; ++i) {
        const int j = lane + (i << 6);
        const int n = j >> 5;
        const float a = bf2f(zr[j]);
        const float b = bf2f(zr[448 + j]);
        const float c = bf2f(zr[896 + j]);
        const float sA = bf2f(zr[1344 + n]);
        const float sB = bf2f(zr[1358 + n]);
        const float sC = bf2f(zr[1372 + n]);
        const float L = a + b + c;
        const float Q = a * sA + b * sB + c * sC;
        lin[i] = L; quad[i] = Q;
        s0 += L; s1 += L * L; s2 += Q; s3 += Q * Q;
    }
    #pragma unroll
    for (int off = 32; off > 0; off >>= 1) {
        s0 += __shfl_xor(s0, off);
        s1 += __shfl_xor(s1, off);
        s2 += __shfl_xor(s2, off);
        s3 += __shfl_xor(s3, off);
    }
    const float inv = 1.0f / 448.0f;
    const float mu0 = s0 * inv, mu1 = s2 * inv;
    const float rs0 = rsqrtf(fmaxf(s1 * inv - mu0 * mu0, 0.f) + 1e-5f);
    const float rs1 = rsqrtf(fmaxf(s3 * inv - mu1 * mu1, 0.f) + 1e-5f);

    #pragma unroll
    for (int i = 0; i < 7; ++i) {
        const int j = lane + (i << 6);
        const float g = gamma[j], bt = beta[j];
        const float ln = (lin[i] - mu0) * rs0 * g + bt;
        const float qn = (quad[i] - mu1) * rs1 * g + bt;
        const float v = dwv * qn + (1.0f - dwv) * ln + x[(size_t)row * D_DIM + j];
        ssm[(size_t)row * D_DIM + j] = f2bf(v);
    }
}

extern "C" void kernel_launch(void* const* d_in, const int* in_sizes, int n_in,
                              void* d_out, int out_size, void* d_ws, size_t ws_size,
                              hipStream_t stream) {
    const float* x    = (const float*)d_in[0];
    const float* Wq   = (const float*)d_in[1];
    const float* Wk   = (const float*)d_in[2];
    const float* Wv   = (const float*)d_in[3];
    const float* Wo   = (const float*)d_in[4];
    const float* SA   = (const float*)d_in[5];
    const float* SB   = (const float*)d_in[6];
    const float* SC   = (const float*)d_in[7];
    const float* dynw = (const float*)d_in[8];
    const float* gma  = (const float*)d_in[9];
    const float* bta  = (const float*)d_in[10];
    float* out = (float*)d_out;

    char* ws = (char*)d_ws;
    // layout (bytes):
    //   Xbf   : [0, 58720256)           65536*448*2   (reused as ssm bf16 after GEMM1)
    //   WcatT : [58720256, 59981824)    1408*448*2
    //   WoT   : [59981824, 60440576)    512*448*2
    //   Z     : [60440576, 244989952)   65536*1408*2
    u16* Xbf   = (u16*)(ws);
    u16* WcatT = (u16*)(ws + 58720256);
    u16* WoT   = (u16*)(ws + 59981824);
    u16* Z     = (u16*)(ws + 60440576);

    prep_wcat<<<dim3(NCAT_PAD), dim3(64), 0, stream>>>(Wq, Wk, Wv, SA, SB, SC, WcatT);
    prep_wo<<<dim3(896), dim3(256), 0, stream>>>(Wo, WoT);
    cvt_x_kernel<<<dim3(28672), dim3(256), 0, stream>>>(x, Xbf);

    // GEMM1: Z = Xbf @ Wcat  (N = 1408 padded)
    gemm_bt<true><<<dim3(NCAT_PAD / 128, M_DIM / 128), dim3(256), 0, stream>>>(
        Xbf, WcatT, (void*)Z, NCAT_PAD, NCAT_PAD);

    // epilogue -> ssm (aliased onto Xbf; GEMM1 finished reading it)
    ssm_epilogue<<<dim3(M_DIM / 4), dim3(256), 0, stream>>>(Z, x, gma, bta, dynw, Xbf);

    // GEMM2: out = ssm @ W_o  (N = 512 padded, store-guard 448), f32 out
    gemm_bt<false><<<dim3(N2_PAD / 128, M_DIM / 128), dim3(256), 0, stream>>>(
        Xbf, WoT, (void*)out, 448, 448);
}

// Round 3
// 448.996 us; speedup vs baseline: 1.0772x; 1.0772x over previous
//
#include <hip/hip_runtime.h>
#include <hip/hip_bf16.h>

// Problem: B=256, S=256, D=448, BS=32, NB=14. M = B*S = 65536.
// Folded formulation:
//   WA[t][j] = sum_l W_q[t][blk(j)*32+l] * SSM_A[blk(j)*32+l][j]   (block-diag fold)
//   a = x@WA, b = x@WB, c = x@WC ; s_g[n] = 0.1 * x @ rowblocksum(W_g)
//   lin = a+b+c ; quad = a*sA + b*sB + c*sC (per 32-block)
//   ssm = dw*LN(quad) + (1-dw)*LN(lin) + x ;  out = ssm @ W_o
//
// GEMM1: X(65536x448) @ Wcat(448x1386, padded N->1408) -> Z bf16
// GEMM2: ssm(65536x448) @ W_o(448x448, padded N->512) -> out f32
//
// R2 changes: BK=64 (two 32-subtile stages per barrier pair, 7 iters not 14),
//             XCD-aware block swizzle on both GEMMs, vectorized epilogue with
//             bf16 residual (reads Xbf not x).

typedef unsigned short u16;
typedef unsigned int u32;
typedef __bf16 bf16x8 __attribute__((ext_vector_type(8)));
typedef float f32x4 __attribute__((ext_vector_type(4)));

#define D_DIM 448
#define M_DIM 65536
#define NCAT 1386
#define NCAT_PAD 1408
#define N2_PAD 512

__device__ __forceinline__ u16 f2bf(float f) {
    union { float f; u32 u; } v; v.f = f;
    u32 u = v.u;
    u32 r = (u + 0x7fffu + ((u >> 16) & 1u)) >> 16;
    return (u16)r;
}
__device__ __forceinline__ float bf2f(u16 h) {
    union { u32 u; float f; } v; v.u = ((u32)h) << 16;
    return v.f;
}

__device__ __forceinline__ void load_lds16(const void* g, void* l) {
    __builtin_amdgcn_global_load_lds(
        (const __attribute__((address_space(1))) void*)g,
        (__attribute__((address_space(3))) void*)l, 16, 0, 0);
}

// ---------------- prep: fold SSM block-diagonals into W, build WcatT (N-major) ----------------
__global__ __launch_bounds__(64) void prep_wcat(
    const float* __restrict__ Wq, const float* __restrict__ Wk, const float* __restrict__ Wv,
    const float* __restrict__ SA, const float* __restrict__ SB, const float* __restrict__ SC,
    u16* __restrict__ WcatT)
{
    const int j = blockIdx.x;
    const int lane = threadIdx.x;
    u16* dst = WcatT + (size_t)j * D_DIM;

    if (j >= NCAT) {            // pad rows -> zero
        for (int t = lane; t < D_DIM; t += 64) dst[t] = 0;
        return;
    }
    if (j < 3 * D_DIM) {        // folded block-diag columns
        const int g = j / D_DIM, jj = j % D_DIM, n = jj >> 5;
        const float* W = (g == 0) ? Wq : (g == 1) ? Wk : Wv;
        const float* Mm = (g == 0) ? SA : (g == 1) ? SB : SC;
        __shared__ float av[32];
        if (lane < 32) av[lane] = Mm[(size_t)(n * 32 + lane) * D_DIM + jj];
        __syncthreads();
        for (int t = lane; t < D_DIM; t += 64) {
            const float* wrow = W + (size_t)t * D_DIM + n * 32;
            float s = 0.f;
            #pragma unroll
            for (int l = 0; l < 32; ++l) s += wrow[l] * av[l];
            dst[t] = f2bf(s);
        }
    } else {                    // 0.1 * block row-sum columns (quad multipliers)
        const int js = j - 3 * D_DIM;
        const int g = js / 14, n = js % 14;
        const float* W = (g == 0) ? Wq : (g == 1) ? Wk : Wv;
        for (int t = lane; t < D_DIM; t += 64) {
            const float* wrow = W + (size_t)t * D_DIM + n * 32;
            float s = 0.f;
            #pragma unroll
            for (int l = 0; l < 32; ++l) s += wrow[l];
            dst[t] = f2bf(0.1f * s);
        }
    }
}

// WoT[o][d] = W_o[d][o], o in [0,512) padded, d in [0,448)
__global__ __launch_bounds__(256) void prep_wo(const float* __restrict__ Wo, u16* __restrict__ WoT) {
    const int idx = blockIdx.x * 256 + threadIdx.x;   // 512*448 total
    const int o = idx / D_DIM, d = idx % D_DIM;
    WoT[idx] = (o < D_DIM) ? f2bf(Wo[(size_t)d * D_DIM + o]) : (u16)0;
}

// x f32 -> bf16
__global__ __launch_bounds__(256) void cvt_x_kernel(const float* __restrict__ x, u16* __restrict__ xb) {
    const size_t i = ((size_t)blockIdx.x * 256 + threadIdx.x) * 4;
    float4 v = *reinterpret_cast<const float4*>(x + i);
    u16 o0 = f2bf(v.x), o1 = f2bf(v.y), o2 = f2bf(v.z), o3 = f2bf(v.w);
    u32 lo = (u32)o0 | ((u32)o1 << 16);
    u32 hi = (u32)o2 | ((u32)o3 << 16);
    u32* p = reinterpret_cast<u32*>(xb + i);
    p[0] = lo; p[1] = hi;
}

// ---------------- 128x128 bf16 GEMM, BK=64 (2x32 subtiles per barrier pair) ----------------
// 1D grid, XCD-swizzled (gridDim.x % 8 == 0 required).
template<bool BF16OUT>
__global__ __launch_bounds__(256) void gemm_bt(
    const u16* __restrict__ A,    // M x 448 bf16 row-major
    const u16* __restrict__ Bt,   // N x 448 bf16 row-major (i.e. B transposed)
    void* __restrict__ Cout,
    int ldc, int nreal, int ncolblk)
{
    __shared__ u16 lA[2][128 * 32];
    __shared__ u16 lB[2][128 * 32];
    const int tid = threadIdx.x;
    const int wave = tid >> 6, lane = tid & 63;

    // XCD swizzle: HW maps bid -> XCD bid%8; give each XCD a contiguous chunk
    const int cpx = gridDim.x >> 3;
    const int bid = blockIdx.x;
    const int t = (bid & 7) * cpx + (bid >> 3);
    const int bx = t % ncolblk, by = t / ncolblk;
    const int brow = by * 128, bcol = bx * 128;
    const int wr = wave >> 1, wc = wave & 1;

    f32x4 acc[4][4];
    #pragma unroll
    for (int i = 0; i < 4; ++i)
        #pragma unroll
        for (int j = 0; j < 4; ++j) {
            f32x4 z = {0.f, 0.f, 0.f, 0.f};
            acc[i][j] = z;
        }

    const int lrow = lane & 15;
    const int kgrp = (lane >> 4) << 3;   // 0,8,16,24

    for (int kt = 0; kt < 7; ++kt) {
        const int k0 = kt * 64;
        // stage two 128x32 subtiles of A and B (per subtile: 512 x 16B chunks)
        #pragma unroll
        for (int ks = 0; ks < 2; ++ks) {
            const int kb = k0 + ks * 32;
            #pragma unroll
            for (int i = 0; i < 2; ++i) {
                const int chunk = (wave * 2 + i) * 64 + lane;     // 0..511
                const int row = chunk >> 2, kk = (chunk & 3) << 3;
                // dest must be wave-uniform; HW adds lane*16B
                load_lds16(A + (size_t)(brow + row) * D_DIM + kb + kk,
                           &lA[ks][(wave * 2 + i) * 512]);
                load_lds16(Bt + (size_t)(bcol + row) * D_DIM + kb + kk,
                           &lB[ks][(wave * 2 + i) * 512]);
            }
        }
        __syncthreads();   // compiler drains vmcnt before barrier

        #pragma unroll
        for (int ks = 0; ks < 2; ++ks) {
            bf16x8 af[4];
            #pragma unroll
            for (int mi = 0; mi < 4; ++mi) {
                const int r = wr * 64 + mi * 16 + lrow;
                af[mi] = *reinterpret_cast<const bf16x8*>(&lA[ks][r * 32 + kgrp]);
            }
            #pragma unroll
            for (int ni = 0; ni < 4; ++ni) {
                const int n = wc * 64 + ni * 16 + lrow;
                bf16x8 bfr = *reinterpret_cast<const bf16x8*>(&lB[ks][n * 32 + kgrp]);
                #pragma unroll
                for (int mi = 0; mi < 4; ++mi)
                    acc[mi][ni] = __builtin_amdgcn_mfma_f32_16x16x32_bf16(af[mi], bfr, acc[mi][ni], 0, 0, 0);
            }
        }
        __syncthreads();
    }

    // epilogue: C/D layout col=lane&15, row=(lane>>4)*4+reg  [m89-verified]
    const int rbase = brow + wr * 64 + ((lane >> 4) << 2);
    const int cbase = bcol + wc * 64 + (lane & 15);
    #pragma unroll
    for (int mi = 0; mi < 4; ++mi) {
        #pragma unroll
        for (int ni = 0; ni < 4; ++ni) {
            const int col = cbase + ni * 16;
            #pragma unroll
            for (int r = 0; r < 4; ++r) {
                const int row = rbase + mi * 16 + r;
                const float v = acc[mi][ni][r];
                if (BF16OUT) {
                    ((u16*)Cout)[(size_t)row * ldc + col] = f2bf(v);
                } else {
                    if (col < nreal)
                        ((float*)Cout)[(size_t)row * nreal + col] = v;
                }
            }
        }
    }
}

// ---------------- row-wise epilogue: LN(lin), LN(quad), blend, residual -> ssm bf16 ----------------
// Vectorized: lane<56 handles 8 consecutive cols (56*8=448). Residual from Xbf (bf16).
__global__ __launch_bounds__(256) void ssm_epilogue(
    const u16* __restrict__ Z, const u16* __restrict__ xb,
    const float* __restrict__ gamma, const float* __restrict__ beta,
    const float* __restrict__ dynw, u16* __restrict__ ssm)
{
    const int row = blockIdx.x * 4 + (threadIdx.x >> 6);
    const int lane = threadIdx.x & 63;
    const u16* zr = Z + (size_t)row * NCAT_PAD;
    const float dwv = 1.0f / (1.0f + __expf(-dynw[0]));
    const bool act = lane < 56;
    const int j0 = lane * 8;                 // 8 consecutive cols, within one 32-block
    const int n = lane >> 2;                 // block index for these 8 cols

    // quad multipliers: zr[1344+n]=sA, [1358+n]=sB, [1372+n]=sC ; distribute by shuffle
    float sv = (lane < 42) ? bf2f(zr[1344 + lane]) : 0.f;
    const float sA = __shfl(sv, n);
    const float sB = __shfl(sv, 14 + n);
    const float sC = __shfl(sv, 28 + n);

    float L[8], Q[8];
    float s0 = 0.f, s1 = 0.f, s2 = 0.f, s3 = 0.f;
    if (act) {
        uint4 va = *reinterpret_cast<const uint4*>(zr + j0);
        uint4 vb = *reinterpret_cast<const uint4*>(zr + 448 + j0);
        uint4 vc = *reinterpret_cast<const uint4*>(zr + 896 + j0);
        const u32* pa = reinterpret_cast<const u32*>(&va);
        const u32* pb = reinterpret_cast<const u32*>(&vb);
        const u32* pc = reinterpret_cast<const u32*>(&vc);
        #pragma unroll
        for (int w = 0; w < 4; ++w) {
            #pragma unroll
            for (int h = 0; h < 2; ++h) {
                const int i = w * 2 + h;
                const float a = bf2f((u16)((pa[w] >> (16 * h)) & 0xffffu));
                const float b = bf2f((u16)((pb[w] >> (16 * h)) & 0xffffu));
                const float c = bf2f((u16)((pc[w] >> (16 * h)) & 0xffffu));
                const float Lv = a + b + c;
                const float Qv = a * sA + b * sB + c * sC;
                L[i] = Lv; Q[i] = Qv;
                s0 += Lv; s1 += Lv * Lv; s2 += Qv; s3 += Qv * Qv;
            }
        }
    } else {
        #pragma unroll
        for (int i = 0; i < 8; ++i) { L[i] = 0.f; Q[i] = 0.f; }
    }
    #pragma unroll
    for (int off = 32; off > 0; off >>= 1) {
        s0 += __shfl_xor(s0, off);
        s1 += __shfl_xor(s1, off);
        s2 += __shfl_xor(s2, off);
        s3 += __shfl_xor(s3, off);
    }
    const float inv = 1.0f / 448.0f;
    const float mu0 = s0 * inv, mu1 = s2 * inv;
    const float rs0 = rsqrtf(fmaxf(s1 * inv - mu0 * mu0, 0.f) + 1e-5f);
    const float rs1 = rsqrtf(fmaxf(s3 * inv - mu1 * mu1, 0.f) + 1e-5f);

    if (act) {
        float4 g0 = *reinterpret_cast<const float4*>(gamma + j0);
        float4 g1 = *reinterpret_cast<const float4*>(gamma + j0 + 4);
        float4 b0 = *reinterpret_cast<const float4*>(beta + j0);
        float4 b1 = *reinterpret_cast<const float4*>(beta + j0 + 4);
        const float* gp = &g0.x;   // g0,g1 contiguous on stack? avoid: use arrays
        float gv[8] = {g0.x, g0.y, g0.z, g0.w, g1.x, g1.y, g1.z, g1.w};
        float bv[8] = {b0.x, b0.y, b0.z, b0.w, b1.x, b1.y, b1.z, b1.w};
        (void)gp;
        uint4 vx = *reinterpret_cast<const uint4*>(xb + (size_t)row * D_DIM + j0);
        const u32* px = reinterpret_cast<const u32*>(&vx);
        u32 outw[4];
        #pragma unroll
        for (int w = 0; w < 4; ++w) {
            u16 h0, h1;
            {
                const int i = w * 2;
                const float xr = bf2f((u16)(px[w] & 0xffffu));
                const float ln = (L[i] - mu0) * rs0 * gv[i] + bv[i];
                const float qn = (Q[i] - mu1) * rs1 * gv[i] + bv[i];
                h0 = f2bf(dwv * qn + (1.0f - dwv) * ln + xr);
            }
            {
                const int i = w * 2 + 1;
                const float xr = bf2f((u16)(px[w] >> 16));
                const float ln = (L[i] - mu0) * rs0 * gv[i] + bv[i];
                const float qn = (Q[i] - mu1) * rs1 * gv[i] + bv[i];
                h1 = f2bf(dwv * qn + (1.0f - dwv) * ln + xr);
            }
            outw[w] = (u32)h0 | ((u32)h1 << 16);
        }
        uint4 ov = {outw[0], outw[1], outw[2], outw[3]};
        *reinterpret_cast<uint4*>(ssm + (size_t)row * D_DIM + j0) = ov;
    }
}

extern "C" void kernel_launch(void* const* d_in, const int* in_sizes, int n_in,
                              void* d_out, int out_size, void* d_ws, size_t ws_size,
                              hipStream_t stream) {
    const float* x    = (const float*)d_in[0];
    const float* Wq   = (const float*)d_in[1];
    const float* Wk   = (const float*)d_in[2];
    const float* Wv   = (const float*)d_in[3];
    const float* Wo   = (const float*)d_in[4];
    const float* SA   = (const float*)d_in[5];
    const float* SB   = (const float*)d_in[6];
    const float* SC   = (const float*)d_in[7];
    const float* dynw = (const float*)d_in[8];
    const float* gma  = (const float*)d_in[9];
    const float* bta  = (const float*)d_in[10];
    float* out = (float*)d_out;

    char* ws = (char*)d_ws;
    // layout (bytes):
    //   Xbf   : [0, 58720256)           65536*448*2   (reused as ssm bf16 after GEMM1)
    //   WcatT : [58720256, 59981824)    1408*448*2
    //   WoT   : [59981824, 60440576)    512*448*2
    //   Z     : [60440576, 244989952)   65536*1408*2
    u16* Xbf   = (u16*)(ws);
    u16* WcatT = (u16*)(ws + 58720256);
    u16* WoT   = (u16*)(ws + 59981824);
    u16* Z     = (u16*)(ws + 60440576);

    prep_wcat<<<dim3(NCAT_PAD), dim3(64), 0, stream>>>(Wq, Wk, Wv, SA, SB, SC, WcatT);
    prep_wo<<<dim3(896), dim3(256), 0, stream>>>(Wo, WoT);
    cvt_x_kernel<<<dim3(28672), dim3(256), 0, stream>>>(x, Xbf);

    // GEMM1: Z = Xbf @ Wcat  (N = 1408 padded); grid 11*512 = 5632 (%8==0)
    gemm_bt<true><<<dim3(5632), dim3(256), 0, stream>>>(
        Xbf, WcatT, (void*)Z, NCAT_PAD, NCAT_PAD, 11);

    // epilogue -> ssm (aliased onto Xbf; reads Xbf for residual, in-place per element)
    ssm_epilogue<<<dim3(M_DIM / 4), dim3(256), 0, stream>>>(Z, Xbf, gma, bta, dynw, Xbf);

    // GEMM2: out = ssm @ W_o  (N = 512 padded, store-guard 448), f32 out; grid 4*512 (%8==0)
    gemm_bt<false><<<dim3(2048), dim3(256), 0, stream>>>(
        Xbf, WoT, (void*)out, 448, 448, 4);
}

// Round 4
// 432.354 us; speedup vs baseline: 1.1187x; 1.0385x over previous
//
#include <hip/hip_runtime.h>
#include <hip/hip_bf16.h>

// Problem: B=256, S=256, D=448, BS=32, NB=14. M = B*S = 65536.
// Folded formulation:
//   WA[t][j] = sum_l W_q[t][blk(j)*32+l] * SSM_A[blk(j)*32+l][j]   (block-diag fold)
//   a = x@WA, b = x@WB, c = x@WC ; s_g[n] = 0.1 * x @ rowblocksum(W_g)
//   lin = a+b+c ; quad = a*sA + b*sB + c*sC (per 32-block)
//   ssm = dw*LN(quad) + (1-dw)*LN(lin) + x ;  out = ssm @ W_o
//
// R4 changes: pipelined double-buffered GEMM (stage t+1 issued before compute t,
//             one barrier per tile, static buffer names), prep kernels merged.

typedef unsigned short u16;
typedef unsigned int u32;
typedef __bf16 bf16x8 __attribute__((ext_vector_type(8)));
typedef float f32x4 __attribute__((ext_vector_type(4)));

#define D_DIM 448
#define M_DIM 65536
#define NCAT 1386
#define NCAT_PAD 1408
#define N2_PAD 512

#define CVT_BLKS 28672          // 65536*448/4/256
#define WO_BLKS 896             // 512*448/256
#define WCAT_BLKS 1408

__device__ __forceinline__ u16 f2bf(float f) {
    union { float f; u32 u; } v; v.f = f;
    u32 u = v.u;
    u32 r = (u + 0x7fffu + ((u >> 16) & 1u)) >> 16;
    return (u16)r;
}
__device__ __forceinline__ float bf2f(u16 h) {
    union { u32 u; float f; } v; v.u = ((u32)h) << 16;
    return v.f;
}

__device__ __forceinline__ void load_lds16(const void* g, void* l) {
    __builtin_amdgcn_global_load_lds(
        (const __attribute__((address_space(1))) void*)g,
        (__attribute__((address_space(3))) void*)l, 16, 0, 0);
}

// ---------------- fused prep: x->bf16 | WoT build | Wcat fold ----------------
__global__ __launch_bounds__(256) void prep_all(
    const float* __restrict__ x,
    const float* __restrict__ Wq, const float* __restrict__ Wk, const float* __restrict__ Wv,
    const float* __restrict__ Wo,
    const float* __restrict__ SA, const float* __restrict__ SB, const float* __restrict__ SC,
    u16* __restrict__ Xbf, u16* __restrict__ WcatT, u16* __restrict__ WoT)
{
    const int bid = blockIdx.x;
    const int tid = threadIdx.x;

    if (bid < CVT_BLKS) {                      // x f32 -> bf16, 4 elems/thread
        const size_t i = ((size_t)bid * 256 + tid) * 4;
        float4 v = *reinterpret_cast<const float4*>(x + i);
        u32 lo = (u32)f2bf(v.x) | ((u32)f2bf(v.y) << 16);
        u32 hi = (u32)f2bf(v.z) | ((u32)f2bf(v.w) << 16);
        u32* p = reinterpret_cast<u32*>(Xbf + i);
        p[0] = lo; p[1] = hi;
        return;
    }
    if (bid < CVT_BLKS + WO_BLKS) {            // WoT[o][d] = Wo[d][o], o padded to 512
        const int idx = (bid - CVT_BLKS) * 256 + tid;
        const int o = idx / D_DIM, d = idx % D_DIM;
        WoT[idx] = (o < D_DIM) ? f2bf(Wo[(size_t)d * D_DIM + o]) : (u16)0;
        return;
    }
    // WcatT row j
    const int j = bid - (CVT_BLKS + WO_BLKS);
    u16* dst = WcatT + (size_t)j * D_DIM;
    if (j >= NCAT) {                           // pad rows
        for (int t = tid; t < D_DIM; t += 256) dst[t] = 0;
        return;
    }
    if (j < 3 * D_DIM) {                       // folded block-diag columns
        const int g = j / D_DIM, jj = j % D_DIM, n = jj >> 5;
        const float* W = (g == 0) ? Wq : (g == 1) ? Wk : Wv;
        const float* Mm = (g == 0) ? SA : (g == 1) ? SB : SC;
        __shared__ float av[32];
        if (tid < 32) av[tid] = Mm[(size_t)(n * 32 + tid) * D_DIM + jj];
        __syncthreads();
        for (int t = tid; t < D_DIM; t += 256) {
            const float* wrow = W + (size_t)t * D_DIM + n * 32;
            float s = 0.f;
            #pragma unroll
            for (int l = 0; l < 32; ++l) s += wrow[l] * av[l];
            dst[t] = f2bf(s);
        }
    } else {                                   // 0.1 * block row-sum columns
        const int js = j - 3 * D_DIM;
        const int g = js / 14, n = js % 14;
        const float* W = (g == 0) ? Wq : (g == 1) ? Wk : Wv;
        for (int t = tid; t < D_DIM; t += 256) {
            const float* wrow = W + (size_t)t * D_DIM + n * 32;
            float s = 0.f;
            #pragma unroll
            for (int l = 0; l < 32; ++l) s += wrow[l];
            dst[t] = f2bf(0.1f * s);
        }
    }
}

// ---------------- pipelined 128x128 bf16 GEMM, BK=32, double-buffered ----------------
// 1D grid, XCD-swizzled (gridDim.x % 8 == 0 required).
template<bool BF16OUT>
__global__ __launch_bounds__(256) void gemm_bt(
    const u16* __restrict__ A,    // M x 448 bf16 row-major
    const u16* __restrict__ Bt,   // N x 448 bf16 row-major (B transposed)
    void* __restrict__ Cout,
    int ldc, int nreal, int ncolblk)
{
    __shared__ u16 lA0[4096], lB0[4096], lA1[4096], lB1[4096];
    const int tid = threadIdx.x;
    const int wave = tid >> 6, lane = tid & 63;

    const int cpx = gridDim.x >> 3;
    const int bid = blockIdx.x;
    const int t = (bid & 7) * cpx + (bid >> 3);
    const int bx = t % ncolblk, by = t / ncolblk;
    const int brow = by * 128, bcol = bx * 128;
    const int wr = wave >> 1, wc = wave & 1;

    f32x4 acc[4][4];
    #pragma unroll
    for (int i = 0; i < 4; ++i)
        #pragma unroll
        for (int jj = 0; jj < 4; ++jj) {
            f32x4 z = {0.f, 0.f, 0.f, 0.f};
            acc[i][jj] = z;
        }

    const int lrow = lane & 15;
    const int kgrp = (lane >> 4) << 3;   // 0,8,16,24

    // staging geometry: tile = 128x32 bf16 = 512 chunks of 16B; 2 chunks/thread/matrix
    const int c0 = wave * 128 + lane;          // (wave*2+0)*64 + lane
    const int c1 = c0 + 64;
    const int row0 = c0 >> 2, kk0 = (c0 & 3) << 3;
    const int row1 = c1 >> 2, kk1 = (c1 & 3) << 3;
    const u16* ga0 = A  + (size_t)(brow + row0) * D_DIM + kk0;
    const u16* ga1 = A  + (size_t)(brow + row1) * D_DIM + kk1;
    const u16* gb0 = Bt + (size_t)(bcol + row0) * D_DIM + kk0;
    const u16* gb1 = Bt + (size_t)(bcol + row1) * D_DIM + kk1;
    const int d0 = wave * 1024, d1 = wave * 1024 + 512;

#define STAGE(LA, LB, koff) do { \
    load_lds16(ga0 + (koff), &LA[d0]); \
    load_lds16(ga1 + (koff), &LA[d1]); \
    load_lds16(gb0 + (koff), &LB[d0]); \
    load_lds16(gb1 + (koff), &LB[d1]); \
} while (0)

#define COMPUTE(LA, LB) do { \
    bf16x8 af[4]; \
    _Pragma("unroll") \
    for (int mi = 0; mi < 4; ++mi) \
        af[mi] = *reinterpret_cast<const bf16x8*>(&LA[(wr * 64 + mi * 16 + lrow) * 32 + kgrp]); \
    _Pragma("unroll") \
    for (int ni = 0; ni < 4; ++ni) { \
        bf16x8 bfr = *reinterpret_cast<const bf16x8*>(&LB[(wc * 64 + ni * 16 + lrow) * 32 + kgrp]); \
        _Pragma("unroll") \
        for (int mi = 0; mi < 4; ++mi) \
            acc[mi][ni] = __builtin_amdgcn_mfma_f32_16x16x32_bf16(af[mi], bfr, acc[mi][ni], 0, 0, 0); \
    } \
} while (0)

    // prologue: stage tile 0
    STAGE(lA0, lB0, 0);
    __syncthreads();

    // 14 K-tiles, software-pipelined: stage t+1 issued before compute t
    for (int kt = 0; kt < 14; kt += 2) {
        STAGE(lA1, lB1, (kt + 1) * 32);
        COMPUTE(lA0, lB0);
        __syncthreads();                       // drains this wave's stage loads, then joins
        if (kt + 2 < 14) STAGE(lA0, lB0, (kt + 2) * 32);
        COMPUTE(lA1, lB1);
        __syncthreads();
    }
#undef STAGE
#undef COMPUTE

    // epilogue: C/D layout col=lane&15, row=(lane>>4)*4+reg  [m89-verified]
    const int rbase = brow + wr * 64 + ((lane >> 4) << 2);
    const int cbase = bcol + wc * 64 + (lane & 15);
    #pragma unroll
    for (int mi = 0; mi < 4; ++mi) {
        #pragma unroll
        for (int ni = 0; ni < 4; ++ni) {
            const int col = cbase + ni * 16;
            #pragma unroll
            for (int r = 0; r < 4; ++r) {
                const int row = rbase + mi * 16 + r;
                const float v = acc[mi][ni][r];
                if (BF16OUT) {
                    ((u16*)Cout)[(size_t)row * ldc + col] = f2bf(v);
                } else {
                    if (col < nreal)
                        ((float*)Cout)[(size_t)row * nreal + col] = v;
                }
            }
        }
    }
}

// ---------------- row-wise epilogue: LN(lin), LN(quad), blend, residual -> ssm bf16 ----------------
__global__ __launch_bounds__(256) void ssm_epilogue(
    const u16* __restrict__ Z, const u16* __restrict__ xb,
    const float* __restrict__ gamma, const float* __restrict__ beta,
    const float* __restrict__ dynw, u16* __restrict__ ssm)
{
    const int row = blockIdx.x * 4 + (threadIdx.x >> 6);
    const int lane = threadIdx.x & 63;
    const u16* zr = Z + (size_t)row * NCAT_PAD;
    const float dwv = 1.0f / (1.0f + __expf(-dynw[0]));
    const bool act = lane < 56;
    const int j0 = lane * 8;                 // 8 consecutive cols, within one 32-block
    const int n = lane >> 2;                 // block index for these 8 cols

    // quad multipliers: zr[1344+n]=sA, [1358+n]=sB, [1372+n]=sC ; distribute by shuffle
    float sv = (lane < 42) ? bf2f(zr[1344 + lane]) : 0.f;
    const float sA = __shfl(sv, n);
    const float sB = __shfl(sv, 14 + n);
    const float sC = __shfl(sv, 28 + n);

    float L[8], Q[8];
    float s0 = 0.f, s1 = 0.f, s2 = 0.f, s3 = 0.f;
    if (act) {
        uint4 va = *reinterpret_cast<const uint4*>(zr + j0);
        uint4 vb = *reinterpret_cast<const uint4*>(zr + 448 + j0);
        uint4 vc = *reinterpret_cast<const uint4*>(zr + 896 + j0);
        const u32* pa = reinterpret_cast<const u32*>(&va);
        const u32* pb = reinterpret_cast<const u32*>(&vb);
        const u32* pc = reinterpret_cast<const u32*>(&vc);
        #pragma unroll
        for (int w = 0; w < 4; ++w) {
            #pragma unroll
            for (int h = 0; h < 2; ++h) {
                const int i = w * 2 + h;
                const float a = bf2f((u16)((pa[w] >> (16 * h)) & 0xffffu));
                const float b = bf2f((u16)((pb[w] >> (16 * h)) & 0xffffu));
                const float c = bf2f((u16)((pc[w] >> (16 * h)) & 0xffffu));
                const float Lv = a + b + c;
                const float Qv = a * sA + b * sB + c * sC;
                L[i] = Lv; Q[i] = Qv;
                s0 += Lv; s1 += Lv * Lv; s2 += Qv; s3 += Qv * Qv;
            }
        }
    } else {
        #pragma unroll
        for (int i = 0; i < 8; ++i) { L[i] = 0.f; Q[i] = 0.f; }
    }
    #pragma unroll
    for (int off = 32; off > 0; off >>= 1) {
        s0 += __shfl_xor(s0, off);
        s1 += __shfl_xor(s1, off);
        s2 += __shfl_xor(s2, off);
        s3 += __shfl_xor(s3, off);
    }
    const float inv = 1.0f / 448.0f;
    const float mu0 = s0 * inv, mu1 = s2 * inv;
    const float rs0 = rsqrtf(fmaxf(s1 * inv - mu0 * mu0, 0.f) + 1e-5f);
    const float rs1 = rsqrtf(fmaxf(s3 * inv - mu1 * mu1, 0.f) + 1e-5f);

    if (act) {
        float4 g0 = *reinterpret_cast<const float4*>(gamma + j0);
        float4 g1 = *reinterpret_cast<const float4*>(gamma + j0 + 4);
        float4 b0 = *reinterpret_cast<const float4*>(beta + j0);
        float4 b1 = *reinterpret_cast<const float4*>(beta + j0 + 4);
        float gv[8] = {g0.x, g0.y, g0.z, g0.w, g1.x, g1.y, g1.z, g1.w};
        float bv[8] = {b0.x, b0.y, b0.z, b0.w, b1.x, b1.y, b1.z, b1.w};
        uint4 vx = *reinterpret_cast<const uint4*>(xb + (size_t)row * D_DIM + j0);
        const u32* px = reinterpret_cast<const u32*>(&vx);
        u32 outw[4];
        #pragma unroll
        for (int w = 0; w < 4; ++w) {
            u16 h0, h1;
            {
                const int i = w * 2;
                const float xr = bf2f((u16)(px[w] & 0xffffu));
                const float ln = (L[i] - mu0) * rs0 * gv[i] + bv[i];
                const float qn = (Q[i] - mu1) * rs1 * gv[i] + bv[i];
                h0 = f2bf(dwv * qn + (1.0f - dwv) * ln + xr);
            }
            {
                const int i = w * 2 + 1;
                const float xr = bf2f((u16)(px[w] >> 16));
                const float ln = (L[i] - mu0) * rs0 * gv[i] + bv[i];
                const float qn = (Q[i] - mu1) * rs1 * gv[i] + bv[i];
                h1 = f2bf(dwv * qn + (1.0f - dwv) * ln + xr);
            }
            outw[w] = (u32)h0 | ((u32)h1 << 16);
        }
        uint4 ov = {outw[0], outw[1], outw[2], outw[3]};
        *reinterpret_cast<uint4*>(ssm + (size_t)row * D_DIM + j0) = ov;
    }
}

extern "C" void kernel_launch(void* const* d_in, const int* in_sizes, int n_in,
                              void* d_out, int out_size, void* d_ws, size_t ws_size,
                              hipStream_t stream) {
    const float* x    = (const float*)d_in[0];
    const float* Wq   = (const float*)d_in[1];
    const float* Wk   = (const float*)d_in[2];
    const float* Wv   = (const float*)d_in[3];
    const float* Wo   = (const float*)d_in[4];
    const float* SA   = (const float*)d_in[5];
    const float* SB   = (const float*)d_in[6];
    const float* SC   = (const float*)d_in[7];
    const float* dynw = (const float*)d_in[8];
    const float* gma  = (const float*)d_in[9];
    const float* bta  = (const float*)d_in[10];
    float* out = (float*)d_out;

    char* ws = (char*)d_ws;
    // layout (bytes):
    //   Xbf   : [0, 58720256)           65536*448*2   (reused as ssm bf16 after GEMM1)
    //   WcatT : [58720256, 59981824)    1408*448*2
    //   WoT   : [59981824, 60440576)    512*448*2
    //   Z     : [60440576, 244989952)   65536*1408*2
    u16* Xbf   = (u16*)(ws);
    u16* WcatT = (u16*)(ws + 58720256);
    u16* WoT   = (u16*)(ws + 59981824);
    u16* Z     = (u16*)(ws + 60440576);

    prep_all<<<dim3(CVT_BLKS + WO_BLKS + WCAT_BLKS), dim3(256), 0, stream>>>(
        x, Wq, Wk, Wv, Wo, SA, SB, SC, Xbf, WcatT, WoT);

    // GEMM1: Z = Xbf @ Wcat  (N = 1408 padded); grid 11*512 = 5632 (%8==0)
    gemm_bt<true><<<dim3(5632), dim3(256), 0, stream>>>(
        Xbf, WcatT, (void*)Z, NCAT_PAD, NCAT_PAD, 11);

    // epilogue -> ssm (aliased onto Xbf; reads Xbf for residual, in-place per element)
    ssm_epilogue<<<dim3(M_DIM / 4), dim3(256), 0, stream>>>(Z, Xbf, gma, bta, dynw, Xbf);

    // GEMM2: out = ssm @ W_o  (N = 512 padded, store-guard 448), f32 out; grid 4*512 (%8==0)
    gemm_bt<false><<<dim3(2048), dim3(256), 0, stream>>>(
        Xbf, WoT, (void*)out, 448, 448, 4);
}

// Round 5
// 429.769 us; speedup vs baseline: 1.1254x; 1.0060x over previous
//
#include <hip/hip_runtime.h>
#include <hip/hip_bf16.h>

// B=256,S=256,D=448,BS=32,NB=14. M=65536.
// Folded: a=x@WA, b=x@WB, c=x@WC (block-diag folded into W); s_g = 0.1*x@rowblocksum(W_g)
// lin=a+b+c; quad=a*sA+b*sB+c*sC; ssm=dw*LN(quad)+(1-dw)*LN(lin)+x; out=ssm@W_o
// GEMM1: X(65536x448) @ Wcat(448x1386; N-tiles padded to 1536, Z stride 1392) -> Z bf16
// GEMM2: ssm(65536x448) @ W_o(448x448, padded 512) -> out f32
// R5: 256x256 8-phase counted-vmcnt GEMM (T3+T4), st-swizzled LDS (T2), setprio (T5).

typedef unsigned short u16;
typedef unsigned int u32;
typedef __bf16 bf16x8 __attribute__((ext_vector_type(8)));
typedef float f32x4 __attribute__((ext_vector_type(4)));

#define D_DIM 448
#define M_DIM 65536
#define NCAT 1386
#define NWCAT 1536          // Wcat rows (6 x 256 col-tiles)
#define ZSTRIDE 1392        // Z row stride (16B-aligned, >= 1386)
#define N2_PAD 512

#define CVT_BLKS 28672      // 65536*448/4/256
#define WO_BLKS 896         // 512*448/256
#define WCAT_BLKS 1536

__device__ __forceinline__ u16 f2bf(float f) {
    union { float f; u32 u; } v; v.f = f;
    u32 u = v.u;
    return (u16)((u + 0x7fffu + ((u >> 16) & 1u)) >> 16);
}
__device__ __forceinline__ float bf2f(u16 h) {
    union { u32 u; float f; } v; v.u = ((u32)h) << 16;
    return v.f;
}
__device__ __forceinline__ void load_lds16(const void* g, void* l) {
    __builtin_amdgcn_global_load_lds(
        (const __attribute__((address_space(1))) void*)g,
        (__attribute__((address_space(3))) void*)l, 16, 0, 0);
}

// ---------------- fused prep: x->bf16 | WoT | Wcat fold ----------------
__global__ __launch_bounds__(256) void prep_all(
    const float* __restrict__ x,
    const float* __restrict__ Wq, const float* __restrict__ Wk, const float* __restrict__ Wv,
    const float* __restrict__ Wo,
    const float* __restrict__ SA, const float* __restrict__ SB, const float* __restrict__ SC,
    u16* __restrict__ Xbf, u16* __restrict__ WcatT, u16* __restrict__ WoT)
{
    const int bid = blockIdx.x;
    const int tid = threadIdx.x;

    if (bid < CVT_BLKS) {
        const size_t i = ((size_t)bid * 256 + tid) * 4;
        float4 v = *reinterpret_cast<const float4*>(x + i);
        u32 lo = (u32)f2bf(v.x) | ((u32)f2bf(v.y) << 16);
        u32 hi = (u32)f2bf(v.z) | ((u32)f2bf(v.w) << 16);
        u32* p = reinterpret_cast<u32*>(Xbf + i);
        p[0] = lo; p[1] = hi;
        return;
    }
    if (bid < CVT_BLKS + WO_BLKS) {
        const int idx = (bid - CVT_BLKS) * 256 + tid;
        const int o = idx / D_DIM, d = idx % D_DIM;
        WoT[idx] = (o < D_DIM) ? f2bf(Wo[(size_t)d * D_DIM + o]) : (u16)0;
        return;
    }
    const int j = bid - (CVT_BLKS + WO_BLKS);
    u16* dst = WcatT + (size_t)j * D_DIM;
    if (j >= NCAT) {
        for (int t = tid; t < D_DIM; t += 256) dst[t] = 0;
        return;
    }
    if (j < 3 * D_DIM) {
        const int g = j / D_DIM, jj = j % D_DIM, n = jj >> 5;
        const float* W = (g == 0) ? Wq : (g == 1) ? Wk : Wv;
        const float* Mm = (g == 0) ? SA : (g == 1) ? SB : SC;
        __shared__ float av[32];
        if (tid < 32) av[tid] = Mm[(size_t)(n * 32 + tid) * D_DIM + jj];
        __syncthreads();
        for (int t = tid; t < D_DIM; t += 256) {
            const float* wrow = W + (size_t)t * D_DIM + n * 32;
            float s = 0.f;
            #pragma unroll
            for (int l = 0; l < 32; ++l) s += wrow[l] * av[l];
            dst[t] = f2bf(s);
        }
    } else {
        const int js = j - 3 * D_DIM;
        const int g = js / 14, n = js % 14;
        const float* W = (g == 0) ? Wq : (g == 1) ? Wk : Wv;
        for (int t = tid; t < D_DIM; t += 256) {
            const float* wrow = W + (size_t)t * D_DIM + n * 32;
            float s = 0.f;
            #pragma unroll
            for (int l = 0; l < 32; ++l) s += wrow[l];
            dst[t] = f2bf(0.1f * s);
        }
    }
}

// ---------------- 256x256 8-phase GEMM, BK=64, K=448 (7 tiles), counted vmcnt ----------------
// LDS 128KB: buf b at b*65536; A half h at +h*16384 (128x64 bf16); B at +32768+h*16384.
// Swizzle: physical byte = logical ^ ((row&7)<<4). global_load_lds dest linear; source pre-swizzled.
// Phase order per tile: (mh,nh) = (0,0),(0,1),(1,1),(1,0).
// Staging during tile t (for t+1, opposite buf): ph1:A0 ph2:B0 ph3:B1 ph4:A1.
// vmcnt(4) at end of ph1, ph2, ph4 (per-wave: 2 loads/half, retires exactly what next phase reads).

#define VMW(N) do { asm volatile("s_waitcnt vmcnt(" #N ")" ::: "memory"); } while (0)

template<bool BF16OUT>
__global__ __launch_bounds__(512, 2) void gemm8p(
    const u16* __restrict__ A,    // M x 448 bf16 row-major
    const u16* __restrict__ Bt,   // N x 448 bf16 row-major (B transposed)
    void* __restrict__ Cout,
    int ldc, int ncstore, int ncolblk)
{
    extern __shared__ char ldsc[];
    const int tid = threadIdx.x;
    const int wave = tid >> 6, lane = tid & 63;
    const int lrow = lane & 15;
    const int wr = wave >> 2, wc = wave & 3;

    const int cpx = gridDim.x >> 3;
    const int bid = blockIdx.x;
    const int tt = (bid & 7) * cpx + (bid >> 3);
    const int bx = tt % ncolblk, by = tt / ncolblk;
    const int brow = by * 256, bcol = bx * 256;

    // staging: half-tile = [128][64] bf16 = 1024 x 16B chunks; thread covers chunks c0, c0+512
    const int c0 = wave * 64 + lane;
    const int r0 = c0 >> 3, r1 = r0 + 64;
    const int sc0 = ((((c0 & 7) << 4) ^ ((r0 & 7) << 4)) >> 1);
    const int sc1 = ((((c0 & 7) << 4) ^ ((r1 & 7) << 4)) >> 1);
    const int off0 = r0 * D_DIM + sc0;
    const int off1 = r1 * D_DIM + sc1;

    // frag LDS byte offsets (within a half region), swizzled
    u32 aoff[4][2], boff[2][2];
    #pragma unroll
    for (int mi = 0; mi < 4; ++mi) {
        const int r = wr * 64 + mi * 16 + lrow;
        #pragma unroll
        for (int ks = 0; ks < 2; ++ks) {
            const int cb = ks * 64 + ((lane >> 4) << 4);
            aoff[mi][ks] = (u32)(((r << 7) + cb) ^ ((r & 7) << 4));
        }
    }
    #pragma unroll
    for (int ni = 0; ni < 2; ++ni) {
        const int r = wc * 32 + ni * 16 + lrow;
        #pragma unroll
        for (int ks = 0; ks < 2; ++ks) {
            const int cb = ks * 64 + ((lane >> 4) << 4);
            boff[ni][ks] = (u32)(((r << 7) + cb) ^ ((r & 7) << 4));
        }
    }

    f32x4 acc[2][4][2][2];
    #pragma unroll
    for (int a0 = 0; a0 < 2; ++a0)
        #pragma unroll
        for (int a1 = 0; a1 < 4; ++a1)
            #pragma unroll
            for (int a2 = 0; a2 < 2; ++a2)
                #pragma unroll
                for (int a3 = 0; a3 < 2; ++a3) {
                    f32x4 z = {0.f, 0.f, 0.f, 0.f};
                    acc[a0][a1][a2][a3] = z;
                }

#define STAGE_HALF(PTR, G0, ISB, H, K0, NBUF) do { \
    const u16* _gs = (PTR) + (size_t)((G0) + (H) * 128) * D_DIM + (K0); \
    char* _lb = ldsc + (NBUF) * 65536 + (ISB) * 32768 + (H) * 16384 + wave * 1024; \
    load_lds16(_gs + off0, _lb); \
    load_lds16(_gs + off1, _lb + 8192); \
} while (0)

#define PHASE(BUF, MH, NH, VMEND, ...) do { \
    bf16x8 af[4][2], bfr[2][2]; \
    { \
        const char* _ab = ldsc + (BUF) * 65536 + (MH) * 16384; \
        _Pragma("unroll") \
        for (int mi = 0; mi < 4; ++mi) \
            _Pragma("unroll") \
            for (int ks = 0; ks < 2; ++ks) \
                af[mi][ks] = *reinterpret_cast<const bf16x8*>(_ab + aoff[mi][ks]); \
        const char* _bb = ldsc + (BUF) * 65536 + 32768 + (NH) * 16384; \
        _Pragma("unroll") \
        for (int ni = 0; ni < 2; ++ni) \
            _Pragma("unroll") \
            for (int ks = 0; ks < 2; ++ks) \
                bfr[ni][ks] = *reinterpret_cast<const bf16x8*>(_bb + boff[ni][ks]); \
    } \
    __VA_ARGS__; \
    __builtin_amdgcn_s_barrier(); \
    asm volatile("s_waitcnt lgkmcnt(0)" ::: "memory"); \
    __builtin_amdgcn_sched_barrier(0); \
    __builtin_amdgcn_s_setprio(1); \
    _Pragma("unroll") \
    for (int ni = 0; ni < 2; ++ni) \
        _Pragma("unroll") \
        for (int mi = 0; mi < 4; ++mi) \
            _Pragma("unroll") \
            for (int ks = 0; ks < 2; ++ks) \
                acc[MH][mi][NH][ni] = __builtin_amdgcn_mfma_f32_16x16x32_bf16( \
                    af[mi][ks], bfr[ni][ks], acc[MH][mi][NH][ni], 0, 0, 0); \
    __builtin_amdgcn_s_setprio(0); \
    VMEND; \
    __builtin_amdgcn_s_barrier(); \
} while (0)

    // prologue: stage tile 0 halves in order A0,B0,B1,A1; wait first two; sync
    STAGE_HALF(A,  brow, 0, 0, 0, 0);
    STAGE_HALF(Bt, bcol, 1, 0, 0, 0);
    STAGE_HALF(Bt, bcol, 1, 1, 0, 0);
    STAGE_HALF(A,  brow, 0, 1, 0, 0);
    VMW(4);
    __builtin_amdgcn_s_barrier();

    for (int t = 0; t < 6; ++t) {
        const int buf = t & 1, nbuf = buf ^ 1;
        const int k1 = (t + 1) * 64;
        PHASE(buf, 0, 0, VMW(4), STAGE_HALF(A,  brow, 0, 0, k1, nbuf));
        PHASE(buf, 0, 1, VMW(4), STAGE_HALF(Bt, bcol, 1, 0, k1, nbuf));
        PHASE(buf, 1, 1, (void)0, STAGE_HALF(Bt, bcol, 1, 1, k1, nbuf));
        PHASE(buf, 1, 0, VMW(4), STAGE_HALF(A,  brow, 0, 1, k1, nbuf));
    }
    // tail tile t=6 in buf0: no staging; drain 2 -> 0
    PHASE(0, 0, 0, VMW(2), (void)0);
    PHASE(0, 0, 1, VMW(0), (void)0);
    PHASE(0, 1, 1, (void)0, (void)0);
    PHASE(0, 1, 0, (void)0, (void)0);

#undef PHASE
#undef STAGE_HALF

    // C-write: 16x16 C/D layout col=lane&15, row=(lane>>4)*4+reg  [m89]
    #pragma unroll
    for (int mh = 0; mh < 2; ++mh)
        #pragma unroll
        for (int mi = 0; mi < 4; ++mi)
            #pragma unroll
            for (int nh = 0; nh < 2; ++nh)
                #pragma unroll
                for (int ni = 0; ni < 2; ++ni) {
                    const int col = bcol + nh * 128 + wc * 32 + ni * 16 + lrow;
                    const int rbase = brow + mh * 128 + wr * 64 + mi * 16 + ((lane >> 4) << 2);
                    #pragma unroll
                    for (int r = 0; r < 4; ++r) {
                        const float v = acc[mh][mi][nh][ni][r];
                        if (BF16OUT) {
                            if (col < ncstore)
                                ((u16*)Cout)[(size_t)(rbase + r) * ldc + col] = f2bf(v);
                        } else {
                            if (col < ncstore)
                                ((float*)Cout)[(size_t)(rbase + r) * ldc + col] = v;
                        }
                    }
                }
}

// ---------------- row-wise epilogue: LN(lin), LN(quad), blend, residual -> ssm bf16 ----------------
__global__ __launch_bounds__(256) void ssm_epilogue(
    const u16* __restrict__ Z, const u16* __restrict__ xb,
    const float* __restrict__ gamma, const float* __restrict__ beta,
    const float* __restrict__ dynw, u16* __restrict__ ssm)
{
    const int row = blockIdx.x * 4 + (threadIdx.x >> 6);
    const int lane = threadIdx.x & 63;
    const u16* zr = Z + (size_t)row * ZSTRIDE;
    const float dwv = 1.0f / (1.0f + __expf(-dynw[0]));
    const bool act = lane < 56;
    const int j0 = lane * 8;
    const int n = lane >> 2;

    float sv = (lane < 42) ? bf2f(zr[1344 + lane]) : 0.f;
    const float sA = __shfl(sv, n);
    const float sB = __shfl(sv, 14 + n);
    const float sC = __shfl(sv, 28 + n);

    float L[8], Q[8];
    float s0 = 0.f, s1 = 0.f, s2 = 0.f, s3 = 0.f;
    if (act) {
        uint4 va = *reinterpret_cast<const uint4*>(zr + j0);
        uint4 vb = *reinterpret_cast<const uint4*>(zr + 448 + j0);
        uint4 vc = *reinterpret_cast<const uint4*>(zr + 896 + j0);
        const u32* pa = reinterpret_cast<const u32*>(&va);
        const u32* pb = reinterpret_cast<const u32*>(&vb);
        const u32* pc = reinterpret_cast<const u32*>(&vc);
        #pragma unroll
        for (int w = 0; w < 4; ++w) {
            #pragma unroll
            for (int h = 0; h < 2; ++h) {
                const int i = w * 2 + h;
                const float a = bf2f((u16)((pa[w] >> (16 * h)) & 0xffffu));
                const float b = bf2f((u16)((pb[w] >> (16 * h)) & 0xffffu));
                const float c = bf2f((u16)((pc[w] >> (16 * h)) & 0xffffu));
                const float Lv = a + b + c;
                const float Qv = a * sA + b * sB + c * sC;
                L[i] = Lv; Q[i] = Qv;
                s0 += Lv; s1 += Lv * Lv; s2 += Qv; s3 += Qv * Qv;
            }
        }
    } else {
        #pragma unroll
        for (int i = 0; i < 8; ++i) { L[i] = 0.f; Q[i] = 0.f; }
    }
    #pragma unroll
    for (int off = 32; off > 0; off >>= 1) {
        s0 += __shfl_xor(s0, off);
        s1 += __shfl_xor(s1, off);
        s2 += __shfl_xor(s2, off);
        s3 += __shfl_xor(s3, off);
    }
    const float inv = 1.0f / 448.0f;
    const float mu0 = s0 * inv, mu1 = s2 * inv;
    const float rs0 = rsqrtf(fmaxf(s1 * inv - mu0 * mu0, 0.f) + 1e-5f);
    const float rs1 = rsqrtf(fmaxf(s3 * inv - mu1 * mu1, 0.f) + 1e-5f);

    if (act) {
        float4 g0 = *reinterpret_cast<const float4*>(gamma + j0);
        float4 g1 = *reinterpret_cast<const float4*>(gamma + j0 + 4);
        float4 b0 = *reinterpret_cast<const float4*>(beta + j0);
        float4 b1 = *reinterpret_cast<const float4*>(beta + j0 + 4);
        float gv[8] = {g0.x, g0.y, g0.z, g0.w, g1.x, g1.y, g1.z, g1.w};
        float bv[8] = {b0.x, b0.y, b0.z, b0.w, b1.x, b1.y, b1.z, b1.w};
        uint4 vx = *reinterpret_cast<const uint4*>(xb + (size_t)row * D_DIM + j0);
        const u32* px = reinterpret_cast<const u32*>(&vx);
        u32 outw[4];
        #pragma unroll
        for (int w = 0; w < 4; ++w) {
            u16 h0, h1;
            {
                const int i = w * 2;
                const float xr = bf2f((u16)(px[w] & 0xffffu));
                const float ln = (L[i] - mu0) * rs0 * gv[i] + bv[i];
                const float qn = (Q[i] - mu1) * rs1 * gv[i] + bv[i];
                h0 = f2bf(dwv * qn + (1.0f - dwv) * ln + xr);
            }
            {
                const int i = w * 2 + 1;
                const float xr = bf2f((u16)(px[w] >> 16));
                const float ln = (L[i] - mu0) * rs0 * gv[i] + bv[i];
                const float qn = (Q[i] - mu1) * rs1 * gv[i] + bv[i];
                h1 = f2bf(dwv * qn + (1.0f - dwv) * ln + xr);
            }
            outw[w] = (u32)h0 | ((u32)h1 << 16);
        }
        uint4 ov = {outw[0], outw[1], outw[2], outw[3]};
        *reinterpret_cast<uint4*>(ssm + (size_t)row * D_DIM + j0) = ov;
    }
}

extern "C" void kernel_launch(void* const* d_in, const int* in_sizes, int n_in,
                              void* d_out, int out_size, void* d_ws, size_t ws_size,
                              hipStream_t stream) {
    const float* x    = (const float*)d_in[0];
    const float* Wq   = (const float*)d_in[1];
    const float* Wk   = (const float*)d_in[2];
    const float* Wv   = (const float*)d_in[3];
    const float* Wo   = (const float*)d_in[4];
    const float* SA   = (const float*)d_in[5];
    const float* SB   = (const float*)d_in[6];
    const float* SC   = (const float*)d_in[7];
    const float* dynw = (const float*)d_in[8];
    const float* gma  = (const float*)d_in[9];
    const float* bta  = (const float*)d_in[10];
    float* out = (float*)d_out;

    char* ws = (char*)d_ws;
    // layout (bytes):
    //   Xbf   : [0, 58720256)              65536*448*2  (reused as ssm bf16)
    //   WcatT : [58720256, 60096512)       1536*448*2
    //   WoT   : [60096512, 60555264)       512*448*2
    //   Z     : [60555264, 243007488)      65536*1392*2
    u16* Xbf   = (u16*)(ws);
    u16* WcatT = (u16*)(ws + 58720256);
    u16* WoT   = (u16*)(ws + 60096512);
    u16* Z     = (u16*)(ws + 60555264);

    (void)hipFuncSetAttribute(reinterpret_cast<const void*>(gemm8p<true>),
                              hipFuncAttributeMaxDynamicSharedMemorySize, 131072);
    (void)hipFuncSetAttribute(reinterpret_cast<const void*>(gemm8p<false>),
                              hipFuncAttributeMaxDynamicSharedMemorySize, 131072);

    prep_all<<<dim3(CVT_BLKS + WO_BLKS + WCAT_BLKS), dim3(256), 0, stream>>>(
        x, Wq, Wk, Wv, Wo, SA, SB, SC, Xbf, WcatT, WoT);

    // GEMM1: Z = Xbf @ Wcat ; grid 256 x 6 = 1536 (%8==0)
    gemm8p<true><<<dim3(1536), dim3(512), 131072, stream>>>(
        Xbf, WcatT, (void*)Z, ZSTRIDE, ZSTRIDE, 6);

    // epilogue -> ssm (in-place over Xbf)
    ssm_epilogue<<<dim3(M_DIM / 4), dim3(256), 0, stream>>>(Z, Xbf, gma, bta, dynw, Xbf);

    // GEMM2: out = ssm @ W_o ; grid 256 x 2 = 512 (%8==0)
    gemm8p<false><<<dim3(512), dim3(512), 131072, stream>>>(
        Xbf, WoT, (void*)out, 448, 448, 2);
}